// Round 1
// 1610.900 us; speedup vs baseline: 1.0061x; 1.0061x over previous
//
#include <hip/hip_runtime.h>
#include <hip/hip_bf16.h>

typedef unsigned short ushort_t;
typedef __attribute__((ext_vector_type(8))) short bf16x8;
typedef __attribute__((ext_vector_type(4))) float f32x4;

#define T_TOK 16384
#define H_DIM 1024
#define E_NUM 16
#define F_DIM 2048
#define TK    32768
#define MAX_TILES 272

// ---------- helpers ----------
static __device__ __forceinline__ unsigned short f2bf(float f) {
    unsigned int u = __builtin_bit_cast(unsigned int, f);
    unsigned int r = (u + 0x7fffu + ((u >> 16) & 1u)) >> 16;
    return (unsigned short)r;
}

#define GLOAD_LDS16(gp, lp) \
    __builtin_amdgcn_global_load_lds( \
        (const __attribute__((address_space(1))) unsigned int*)(gp), \
        (__attribute__((address_space(3))) unsigned int*)(lp), 16, 0, 0)

// meta layout (ints): [0..15] cnt, [16..32] offs, [40..55] cursor, [64] ntiles,
// [128..] tile table {row0,row_end,expert}*MAX_TILES
__global__ void k_hist(const int* __restrict__ ids, int* __restrict__ meta) {
    __shared__ int h[E_NUM];
    int tid = threadIdx.x;
    if (tid < E_NUM) h[tid] = 0;
    __syncthreads();
    int i = blockIdx.x * 256 + tid;
    atomicAdd(&h[ids[i]], 1);
    __syncthreads();
    if (tid < E_NUM) atomicAdd(&meta[tid], h[tid]);
}

__global__ void k_scan(int* __restrict__ meta) {
    if (threadIdx.x != 0) return;
    int off = 0;
    for (int e = 0; e < E_NUM; ++e) {
        meta[16 + e] = off;
        meta[40 + e] = off;   // cursor
        off += meta[e];
    }
    meta[32] = off;
    int nt = 0;
    for (int e = 0; e < E_NUM; ++e) {
        int s = meta[16 + e], en = s + meta[e];
        for (int r = s; r < en; r += 128) {
            meta[128 + nt * 3 + 0] = r;
            meta[128 + nt * 3 + 1] = en;
            meta[128 + nt * 3 + 2] = e;
            ++nt;
        }
    }
    meta[64] = nt;
}

__global__ void k_scatter(const int* __restrict__ ids, int* __restrict__ meta,
                          int* __restrict__ row2slot, int* __restrict__ pos2slot) {
    int i = blockIdx.x * 256 + threadIdx.x;
    int e = ids[i];
    int p = atomicAdd(&meta[40 + e], 1);
    row2slot[p] = i;
    pos2slot[i] = p;
}

// gather sorted rows of hidden_states -> bf16 A1 [TK][H]
__global__ void k_gather(const float* __restrict__ hs, const int* __restrict__ row2slot,
                         ushort_t* __restrict__ A1) {
    int r = blockIdx.x;
    int tid = threadIdx.x;
    int tok = row2slot[r] >> 1;           // K=2
    float4 v = *(const float4*)(hs + (size_t)tok * H_DIM + tid * 4);
    ushort4 o;
    o.x = f2bf(v.x); o.y = f2bf(v.y); o.z = f2bf(v.z); o.w = f2bf(v.w);
    *(ushort4*)(A1 + (size_t)r * H_DIM + tid * 4) = o;
}

// gate_up_proj [E][H][2F] f32 -> W1g [E][F][H] bf16 (even cols), W1u (odd cols), k-major
__global__ void k_w1conv(const float* __restrict__ gu, ushort_t* __restrict__ w1g,
                         ushort_t* __restrict__ w1u) {
    __shared__ float t[64][65];
    int b = blockIdx.x;
    int nt = b & 63;            // 64 tiles over 2F=4096
    int kt = (b >> 6) & 15;     // 16 tiles over H=1024
    int e  = b >> 10;
    int n0 = nt * 64, k0 = kt * 64;
    const float* src = gu + ((size_t)e * H_DIM + k0) * (2 * F_DIM) + n0;
    for (int i = threadIdx.x; i < 64 * 64; i += 256) {
        int kr = i >> 6, nc = i & 63;
        t[kr][nc] = src[(size_t)kr * (2 * F_DIM) + nc];
    }
    __syncthreads();
    ushort_t* dg = w1g + ((size_t)e * F_DIM + (n0 >> 1)) * H_DIM + k0;
    ushort_t* du = w1u + ((size_t)e * F_DIM + (n0 >> 1)) * H_DIM + k0;
    for (int i = threadIdx.x; i < 32 * 64; i += 256) {
        int jl = i >> 6, kc = i & 63;
        dg[(size_t)jl * H_DIM + kc] = f2bf(t[kc][2 * jl]);
        du[(size_t)jl * H_DIM + kc] = f2bf(t[kc][2 * jl + 1]);
    }
}

// down_proj [E][F][H] f32 -> W2t [E][H][F] bf16 (k-major over F)
__global__ void k_w2conv(const float* __restrict__ dp, ushort_t* __restrict__ w2t) {
    __shared__ float t[64][65];
    int b = blockIdx.x;
    int ht = b & 15;            // 16 tiles over H
    int ft = (b >> 4) & 31;     // 32 tiles over F
    int e  = b >> 9;
    int h0 = ht * 64, f0 = ft * 64;
    const float* src = dp + ((size_t)e * F_DIM + f0) * H_DIM + h0;
    for (int i = threadIdx.x; i < 64 * 64; i += 256) {
        int fr = i >> 6, hc = i & 63;
        t[fr][hc] = src[(size_t)fr * H_DIM + hc];
    }
    __syncthreads();
    ushort_t* d = w2t + ((size_t)e * H_DIM + h0) * F_DIM + f0;
    for (int i = threadIdx.x; i < 64 * 64; i += 256) {
        int hl = i >> 6, fc = i & 63;
        d[(size_t)hl * F_DIM + fc] = f2bf(t[fc][hl]);
    }
}

// GEMM1: A1[TK][1024] x (W1g/W1u) -> inter[TK][2048] bf16, fused GLU
// grid = (32 j-tiles [x, fastest], MAX_TILES slots [y]).
// 2-phase double-buffered pipeline (T3-minimum): issue next K-tile's
// global_load_lds BEFORE computing the current one; ONE barrier per K-step.
// The __syncthreads() at loop end drains vmcnt(0) after the prefetch had the
// whole ds_read+MFMA phase (~350 cyc) to land, instead of stalling cold.
__global__ __launch_bounds__(256) void k_gemm1(
    const ushort_t* __restrict__ A1, const ushort_t* __restrict__ W1g,
    const ushort_t* __restrict__ W1u, const float* __restrict__ bias,
    ushort_t* __restrict__ inter, const int* __restrict__ meta) {
    int nt = meta[64];
    int slot = blockIdx.y;
    if (slot >= nt) return;
    int row0    = meta[128 + slot * 3 + 0];
    int row_end = meta[128 + slot * 3 + 1];
    int e       = meta[128 + slot * 3 + 2];
    int j0 = blockIdx.x * 64;
    int tid = threadIdx.x, lane = tid & 63, wid = tid >> 6;
    int wm = wid & 1, wj = wid >> 1;
    int lm = lane & 15, lq = lane >> 4;
    __shared__ char smem[2][32 * 1024];   // double-buffered: 16 A + 8 Bg + 8 Bu per buf

    // Hoist per-fragment global base addresses out of the K-loop (kb added per step).
    const ushort_t* gbase[8];
#pragma unroll
    for (int f = 0; f < 8; ++f) {
        int fr = wid * 8 + f;
        const ushort_t* gp;
        if (fr < 16) {
            int mi = fr >> 1, kc = fr & 1;
            int r = row0 + mi * 16 + lm;
            if (r > TK - 1) r = TK - 1;
            gp = A1 + ((size_t)r << 10) + kc * 32 + lq * 8;
        } else if (fr < 24) {
            int g2 = fr - 16; int ji = g2 >> 1, kc = g2 & 1;
            int j = j0 + ji * 16 + lm;
            gp = W1g + (((size_t)(e * F_DIM + j)) << 10) + kc * 32 + lq * 8;
        } else {
            int g2 = fr - 24; int ji = g2 >> 1, kc = g2 & 1;
            int j = j0 + ji * 16 + lm;
            gp = W1u + (((size_t)(e * F_DIM + j)) << 10) + kc * 32 + lq * 8;
        }
        gbase[f] = gp;
    }

    auto stage = [&](int buf, int kb) {
#pragma unroll
        for (int f = 0; f < 8; ++f)
            GLOAD_LDS16(gbase[f] + kb, smem[buf] + (wid * 8 + f) * 1024);
    };

    f32x4 accg[4][2], accu[4][2];
#pragma unroll
    for (int mi = 0; mi < 4; ++mi)
#pragma unroll
        for (int ji = 0; ji < 2; ++ji) {
            accg[mi][ji] = (f32x4){0.f, 0.f, 0.f, 0.f};
            accu[mi][ji] = (f32x4){0.f, 0.f, 0.f, 0.f};
        }

    stage(0, 0);
    __syncthreads();   // prologue: tile 0 resident in buf 0

    for (int kt = 0; kt < 16; ++kt) {
        int cb = kt & 1;
        if (kt < 15) stage(cb ^ 1, (kt + 1) * 64);   // prefetch next tile
        const char* base = smem[cb];
#pragma unroll
        for (int kc = 0; kc < 2; ++kc) {
            bf16x8 af[4], bg[2], bu[2];
#pragma unroll
            for (int mi = 0; mi < 4; ++mi)
                af[mi] = *(const bf16x8*)(base + ((wm * 4 + mi) * 2 + kc) * 1024 + lane * 16);
#pragma unroll
            for (int ji = 0; ji < 2; ++ji) {
                bg[ji] = *(const bf16x8*)(base + 16 * 1024 + ((wj * 2 + ji) * 2 + kc) * 1024 + lane * 16);
                bu[ji] = *(const bf16x8*)(base + 24 * 1024 + ((wj * 2 + ji) * 2 + kc) * 1024 + lane * 16);
            }
#pragma unroll
            for (int mi = 0; mi < 4; ++mi)
#pragma unroll
                for (int ji = 0; ji < 2; ++ji) {
                    accg[mi][ji] = __builtin_amdgcn_mfma_f32_16x16x32_bf16(af[mi], bg[ji], accg[mi][ji], 0, 0, 0);
                    accu[mi][ji] = __builtin_amdgcn_mfma_f32_16x16x32_bf16(af[mi], bu[ji], accu[mi][ji], 0, 0, 0);
                }
        }
        __syncthreads();   // drains this wave's prefetch (had full compute to land) + guards buf reuse
    }

    // epilogue: bias + clamp + GLU, write bf16 intermediate
#pragma unroll
    for (int mi = 0; mi < 4; ++mi)
#pragma unroll
        for (int ji = 0; ji < 2; ++ji) {
            int j = j0 + (wj * 2 + ji) * 16 + lm;
            float bgv = bias[e * (2 * F_DIM) + 2 * j];
            float buv = bias[e * (2 * F_DIM) + 2 * j + 1];
#pragma unroll
            for (int r = 0; r < 4; ++r) {
                int row = row0 + wm * 64 + mi * 16 + lq * 4 + r;
                if (row < row_end) {
                    float g = accg[mi][ji][r] + bgv;
                    g = fminf(g, 7.0f);
                    float u = accu[mi][ji][r] + buv;
                    u = fminf(fmaxf(u, -7.0f), 7.0f);
                    float glu = g / (1.0f + __expf(-1.702f * g));
                    inter[((size_t)row << 11) + j] = f2bf((u + 1.0f) * glu);
                }
            }
        }
}

// GEMM2: inter[TK][2048] x W2t[e][1024][2048] -> out2 f32 [TK][1024]
// grid = (8 n-tiles [x, fastest], MAX_TILES slots [y]); same 2-phase pipeline.
__global__ __launch_bounds__(256) void k_gemm2(
    const ushort_t* __restrict__ Ain, const ushort_t* __restrict__ W2t,
    float* __restrict__ out2, const int* __restrict__ meta) {
    int nt = meta[64];
    int slot = blockIdx.y;
    if (slot >= nt) return;
    int row0    = meta[128 + slot * 3 + 0];
    int row_end = meta[128 + slot * 3 + 1];
    int e       = meta[128 + slot * 3 + 2];
    int n0 = blockIdx.x * 128;
    int tid = threadIdx.x, lane = tid & 63, wid = tid >> 6;
    int wm = wid & 1, wn = wid >> 1;
    int lm = lane & 15, lq = lane >> 4;
    __shared__ char smem[2][32 * 1024];   // double-buffered: 16 A + 16 B per buf

    const ushort_t* gbase[8];
#pragma unroll
    for (int f = 0; f < 8; ++f) {
        int fr = wid * 8 + f;
        const ushort_t* gp;
        if (fr < 16) {
            int mi = fr >> 1, kc = fr & 1;
            int r = row0 + mi * 16 + lm;
            if (r > TK - 1) r = TK - 1;
            gp = Ain + ((size_t)r << 11) + kc * 32 + lq * 8;
        } else {
            int g2 = fr - 16; int ni = g2 >> 1, kc = g2 & 1;
            int n = n0 + ni * 16 + lm;
            gp = W2t + (((size_t)(e * H_DIM + n)) << 11) + kc * 32 + lq * 8;
        }
        gbase[f] = gp;
    }

    auto stage = [&](int buf, int kb) {
#pragma unroll
        for (int f = 0; f < 8; ++f)
            GLOAD_LDS16(gbase[f] + kb, smem[buf] + (wid * 8 + f) * 1024);
    };

    f32x4 acc[4][4];
#pragma unroll
    for (int mi = 0; mi < 4; ++mi)
#pragma unroll
        for (int ni = 0; ni < 4; ++ni) acc[mi][ni] = (f32x4){0.f, 0.f, 0.f, 0.f};

    stage(0, 0);
    __syncthreads();

    for (int kt = 0; kt < 32; ++kt) {
        int cb = kt & 1;
        if (kt < 31) stage(cb ^ 1, (kt + 1) * 64);
        const char* base = smem[cb];
#pragma unroll
        for (int kc = 0; kc < 2; ++kc) {
            bf16x8 af[4], bfr[4];
#pragma unroll
            for (int mi = 0; mi < 4; ++mi)
                af[mi] = *(const bf16x8*)(base + ((wm * 4 + mi) * 2 + kc) * 1024 + lane * 16);
#pragma unroll
            for (int ni = 0; ni < 4; ++ni)
                bfr[ni] = *(const bf16x8*)(base + 16 * 1024 + ((wn * 4 + ni) * 2 + kc) * 1024 + lane * 16);
#pragma unroll
            for (int mi = 0; mi < 4; ++mi)
#pragma unroll
                for (int ni = 0; ni < 4; ++ni)
                    acc[mi][ni] = __builtin_amdgcn_mfma_f32_16x16x32_bf16(af[mi], bfr[ni], acc[mi][ni], 0, 0, 0);
        }
        __syncthreads();
    }
#pragma unroll
    for (int mi = 0; mi < 4; ++mi)
#pragma unroll
        for (int ni = 0; ni < 4; ++ni) {
            int n = n0 + (wn * 4 + ni) * 16 + lm;
#pragma unroll
            for (int r = 0; r < 4; ++r) {
                int row = row0 + wm * 64 + mi * 16 + lq * 4 + r;
                if (row < row_end)
                    out2[((size_t)row << 10) + n] = acc[mi][ni][r];
            }
        }
}

// combine: out[t][h] = sum_k w[t][k] * (out2[pos(t,k)][h] + down_bias[e(t,k)][h])
__global__ void k_combine(const float* __restrict__ out2, const float* __restrict__ tw,
                          const int* __restrict__ ids, const float* __restrict__ db,
                          const int* __restrict__ pos2slot, float* __restrict__ out) {
    int t = blockIdx.x;
    int tid = threadIdx.x;
    float w0 = tw[2 * t], w1 = tw[2 * t + 1];
    int p0 = pos2slot[2 * t], p1 = pos2slot[2 * t + 1];
    int e0 = ids[2 * t], e1 = ids[2 * t + 1];
    int h = tid * 4;
    float4 a0 = *(const float4*)(out2 + ((size_t)p0 << 10) + h);
    float4 a1 = *(const float4*)(out2 + ((size_t)p1 << 10) + h);
    float4 b0 = *(const float4*)(db + ((size_t)e0 << 10) + h);
    float4 b1 = *(const float4*)(db + ((size_t)e1 << 10) + h);
    float4 o;
    o.x = w0 * (a0.x + b0.x) + w1 * (a1.x + b1.x);
    o.y = w0 * (a0.y + b0.y) + w1 * (a1.y + b1.y);
    o.z = w0 * (a0.z + b0.z) + w1 * (a1.z + b1.z);
    o.w = w0 * (a0.w + b0.w) + w1 * (a1.w + b1.w);
    *(float4*)(out + (size_t)t * H_DIM + h) = o;
}

// ---------- workspace layout (bytes) ----------
#define WS_META      0              // 8192
#define WS_R2S       8192           // 131072
#define WS_P2S       139264        // 131072 -> 270336
#define WS_A1        270336        // 67108864 -> 67379200   (bf16 A)
#define WS_W1G       67379200      // 67108864 -> 134488064  (reused as out2 f32 after gemm1)
#define WS_W1U       134488064     // 67108864 -> 201596928
#define WS_W2T       201596928     // 67108864 -> 268705792
#define WS_INTER     268705792     // 134217728 -> 402923520

extern "C" void kernel_launch(void* const* d_in, const int* in_sizes, int n_in,
                              void* d_out, int out_size, void* d_ws, size_t ws_size,
                              hipStream_t stream) {
    (void)in_sizes; (void)n_in; (void)out_size; (void)ws_size;
    const float* hs  = (const float*)d_in[0];
    const float* tw  = (const float*)d_in[1];
    const int*   ids = (const int*)d_in[2];
    const float* gup = (const float*)d_in[3];
    const float* gub = (const float*)d_in[4];
    const float* dp  = (const float*)d_in[5];
    const float* dpb = (const float*)d_in[6];
    float* out = (float*)d_out;
    char* ws = (char*)d_ws;

    int* meta          = (int*)(ws + WS_META);
    int* row2slot      = (int*)(ws + WS_R2S);
    int* pos2slot      = (int*)(ws + WS_P2S);
    ushort_t* A1       = (ushort_t*)(ws + WS_A1);
    ushort_t* W1g      = (ushort_t*)(ws + WS_W1G);
    ushort_t* W1u      = (ushort_t*)(ws + WS_W1U);
    ushort_t* W2t      = (ushort_t*)(ws + WS_W2T);
    ushort_t* inter    = (ushort_t*)(ws + WS_INTER);
    float* out2        = (float*)(ws + WS_W1G);   // alias: W1g/W1u dead after gemm1

    hipMemsetAsync(meta, 0, 8192, stream);
    k_hist<<<128, 256, 0, stream>>>(ids, meta);
    k_scan<<<1, 64, 0, stream>>>(meta);
    k_scatter<<<128, 256, 0, stream>>>(ids, meta, row2slot, pos2slot);
    k_gather<<<TK, 256, 0, stream>>>(hs, row2slot, A1);
    k_w1conv<<<16384, 256, 0, stream>>>(gup, W1g, W1u);
    k_w2conv<<<8192, 256, 0, stream>>>(dp, W2t);
    k_gemm1<<<dim3(32, MAX_TILES), 256, 0, stream>>>(A1, W1g, W1u, gub, inter, meta);
    k_gemm2<<<dim3(8, MAX_TILES), 256, 0, stream>>>(inter, W2t, out2, meta);
    k_combine<<<T_TOK, 256, 0, stream>>>(out2, tw, ids, dpb, pos2slot, out);
}

// Round 2
// 1461.904 us; speedup vs baseline: 1.1087x; 1.1019x over previous
//
#include <hip/hip_runtime.h>
#include <hip/hip_bf16.h>

typedef unsigned short ushort_t;
typedef __attribute__((ext_vector_type(8))) short bf16x8;
typedef __attribute__((ext_vector_type(4))) float f32x4;

#define T_TOK 16384
#define H_DIM 1024
#define E_NUM 16
#define F_DIM 2048
#define TK    32768
#define MAX_TILES 160   // 256-row tiles: <= 32768/256 + 16 = 144

// ---------- helpers ----------
static __device__ __forceinline__ unsigned short f2bf(float f) {
    unsigned int u = __builtin_bit_cast(unsigned int, f);
    unsigned int r = (u + 0x7fffu + ((u >> 16) & 1u)) >> 16;
    return (unsigned short)r;
}

#define GLOAD_LDS16(gp, lp) \
    __builtin_amdgcn_global_load_lds( \
        (const __attribute__((address_space(1))) unsigned int*)(gp), \
        (__attribute__((address_space(3))) unsigned int*)(lp), 16, 0, 0)

#define SBAR()    asm volatile("s_barrier" ::: "memory")
#define WAIT_VM6() asm volatile("s_waitcnt vmcnt(6)" ::: "memory")
#define WAIT_VM0() asm volatile("s_waitcnt vmcnt(0)" ::: "memory")

// meta layout (ints): [0..15] cnt, [16..32] offs, [40..55] cursor, [64] ntiles,
// [128..] tile table {row0,row_end,expert}*MAX_TILES  (256-row tiles)
__global__ void k_hist(const int* __restrict__ ids, int* __restrict__ meta) {
    __shared__ int h[E_NUM];
    int tid = threadIdx.x;
    if (tid < E_NUM) h[tid] = 0;
    __syncthreads();
    int i = blockIdx.x * 256 + tid;
    atomicAdd(&h[ids[i]], 1);
    __syncthreads();
    if (tid < E_NUM) atomicAdd(&meta[tid], h[tid]);
}

__global__ void k_scan(int* __restrict__ meta) {
    if (threadIdx.x != 0) return;
    int off = 0;
    for (int e = 0; e < E_NUM; ++e) {
        meta[16 + e] = off;
        meta[40 + e] = off;   // cursor
        off += meta[e];
    }
    meta[32] = off;
    int nt = 0;
    for (int e = 0; e < E_NUM; ++e) {
        int s = meta[16 + e], en = s + meta[e];
        for (int r = s; r < en; r += 256) {
            meta[128 + nt * 3 + 0] = r;
            meta[128 + nt * 3 + 1] = en;
            meta[128 + nt * 3 + 2] = e;
            ++nt;
        }
    }
    meta[64] = nt;
}

__global__ void k_scatter(const int* __restrict__ ids, int* __restrict__ meta,
                          int* __restrict__ row2slot, int* __restrict__ pos2slot) {
    int i = blockIdx.x * 256 + threadIdx.x;
    int e = ids[i];
    int p = atomicAdd(&meta[40 + e], 1);
    row2slot[p] = i;
    pos2slot[i] = p;
}

// gather sorted rows of hidden_states -> bf16 A1 [TK][H]
__global__ void k_gather(const float* __restrict__ hs, const int* __restrict__ row2slot,
                         ushort_t* __restrict__ A1) {
    int r = blockIdx.x;
    int tid = threadIdx.x;
    int tok = row2slot[r] >> 1;           // K=2
    float4 v = *(const float4*)(hs + (size_t)tok * H_DIM + tid * 4);
    ushort4 o;
    o.x = f2bf(v.x); o.y = f2bf(v.y); o.z = f2bf(v.z); o.w = f2bf(v.w);
    *(ushort4*)(A1 + (size_t)r * H_DIM + tid * 4) = o;
}

// gate_up_proj [E][H][2F] f32 -> W1g [E][F][H] bf16 (even cols), W1u (odd cols), k-major
__global__ void k_w1conv(const float* __restrict__ gu, ushort_t* __restrict__ w1g,
                         ushort_t* __restrict__ w1u) {
    __shared__ float t[64][65];
    int b = blockIdx.x;
    int nt = b & 63;            // 64 tiles over 2F=4096
    int kt = (b >> 6) & 15;     // 16 tiles over H=1024
    int e  = b >> 10;
    int n0 = nt * 64, k0 = kt * 64;
    const float* src = gu + ((size_t)e * H_DIM + k0) * (2 * F_DIM) + n0;
    for (int i = threadIdx.x; i < 64 * 64; i += 256) {
        int kr = i >> 6, nc = i & 63;
        t[kr][nc] = src[(size_t)kr * (2 * F_DIM) + nc];
    }
    __syncthreads();
    ushort_t* dg = w1g + ((size_t)e * F_DIM + (n0 >> 1)) * H_DIM + k0;
    ushort_t* du = w1u + ((size_t)e * F_DIM + (n0 >> 1)) * H_DIM + k0;
    for (int i = threadIdx.x; i < 32 * 64; i += 256) {
        int jl = i >> 6, kc = i & 63;
        dg[(size_t)jl * H_DIM + kc] = f2bf(t[kc][2 * jl]);
        du[(size_t)jl * H_DIM + kc] = f2bf(t[kc][2 * jl + 1]);
    }
}

// down_proj [E][F][H] f32 -> W2t [E][H][F] bf16 (k-major over F)
__global__ void k_w2conv(const float* __restrict__ dp, ushort_t* __restrict__ w2t) {
    __shared__ float t[64][65];
    int b = blockIdx.x;
    int ht = b & 15;            // 16 tiles over H
    int ft = (b >> 4) & 31;     // 32 tiles over F
    int e  = b >> 9;
    int h0 = ht * 64, f0 = ft * 64;
    const float* src = dp + ((size_t)e * F_DIM + f0) * H_DIM + h0;
    for (int i = threadIdx.x; i < 64 * 64; i += 256) {
        int fr = i >> 6, hc = i & 63;
        t[fr][hc] = src[(size_t)fr * H_DIM + hc];
    }
    __syncthreads();
    ushort_t* d = w2t + ((size_t)e * H_DIM + h0) * F_DIM + f0;
    for (int i = threadIdx.x; i < 64 * 64; i += 256) {
        int hl = i >> 6, fc = i & 63;
        d[(size_t)hl * F_DIM + fc] = f2bf(t[fc][hl]);
    }
}

// GEMM1: A1[TK][1024] x (W1g/W1u) -> inter[TK][2048] bf16, fused GLU.
// 256-row tiles, 8 waves (2M x 4N), per-wave 128 rows x 16 j (g+u).
// 8-phase-style schedule: 4 phases per K-tile (BK=64), triple-buffered LDS
// (3 x 48KB), counted s_waitcnt vmcnt(6) at tile top (never 0 in steady
// state), raw s_barrier, setprio(1) around MFMA clusters (T3+T4+T5).
// Per wave per K-tile: exactly 6 global_load_lds (staging tile t+2).
__global__ __launch_bounds__(512) void k_gemm1(
    const ushort_t* __restrict__ A1, const ushort_t* __restrict__ W1g,
    const ushort_t* __restrict__ W1u, const float* __restrict__ bias,
    ushort_t* __restrict__ inter, const int* __restrict__ meta) {
    int nt = meta[64];
    int slot = blockIdx.y;
    if (slot >= nt) return;
    int row0    = meta[128 + slot * 3 + 0];
    int row_end = meta[128 + slot * 3 + 1];
    int e       = meta[128 + slot * 3 + 2];
    int j0 = blockIdx.x * 64;
    int tid = threadIdx.x, lane = tid & 63, wid = tid >> 6;  // wid 0..7
    int wm = wid & 1, wj = wid >> 1;                          // wm M-half, wj 0..3 j-group
    int lm = lane & 15, lq = lane >> 4;
    __shared__ char smem[3][48 * 1024];   // per buf: 32 A frags (32K) + 8 Bg (8K) + 8 Bu (8K)

    // wave's 6 staging fragments: global base (k added per tile) + LDS offset
    const ushort_t* gbase[6];
    int ldsoff[6];
#pragma unroll
    for (int i = 0; i < 6; ++i) {
        int f = wid * 6 + i;
        if (f < 32) {                       // A frag: m_block = f>>1, kc = f&1
            int mb = f >> 1, kc = f & 1;
            int r = row0 + mb * 16 + lm;
            if (r > TK - 1) r = TK - 1;
            gbase[i] = A1 + ((size_t)r << 10) + kc * 32 + lq * 8;
            ldsoff[i] = f * 1024;
        } else if (f < 40) {                // Bg frag: q = jj*2+kc
            int q = f - 32; int jj = q >> 1, kc = q & 1;
            int j = j0 + jj * 16 + lm;
            gbase[i] = W1g + (((size_t)(e * F_DIM + j)) << 10) + kc * 32 + lq * 8;
            ldsoff[i] = 32768 + q * 1024;
        } else {                            // Bu frag
            int q = f - 40; int jj = q >> 1, kc = q & 1;
            int j = j0 + jj * 16 + lm;
            gbase[i] = W1u + (((size_t)(e * F_DIM + j)) << 10) + kc * 32 + lq * 8;
            ldsoff[i] = 40960 + q * 1024;
        }
    }

    f32x4 accg[8], accu[8];
#pragma unroll
    for (int mi = 0; mi < 8; ++mi) {
        accg[mi] = (f32x4){0.f, 0.f, 0.f, 0.f};
        accu[mi] = (f32x4){0.f, 0.f, 0.f, 0.f};
    }

    char* b0 = (char*)smem;            // tile t
    char* b1 = b0 + 49152;             // tile t+1
    char* b2 = b0 + 98304;             // stage target (tile t+2)
#pragma unroll
    for (int i = 0; i < 6; ++i) GLOAD_LDS16(gbase[i], b0 + ldsoff[i]);       // tile 0
#pragma unroll
    for (int i = 0; i < 6; ++i) GLOAD_LDS16(gbase[i] + 64, b1 + ldsoff[i]);  // tile 1

    for (int t = 0; t < 16; ++t) {
        // outstanding: own 6 (tile t) + 6 (tile t+1) => vmcnt(6) retires tile t's.
        if (t == 15) { WAIT_VM0(); } else { WAIT_VM6(); }
        SBAR();
        bool st = (t < 14);
        int kb2 = (t + 2) * 64;
        bf16x8 bg[2], bu[2];
#pragma unroll
        for (int p = 0; p < 4; ++p) {
            bf16x8 af[2][2];
#pragma unroll
            for (int m2 = 0; m2 < 2; ++m2)
#pragma unroll
                for (int kc = 0; kc < 2; ++kc)
                    af[m2][kc] = *(const bf16x8*)(b0 + ((wm * 8 + p * 2 + m2) * 2 + kc) * 1024 + lane * 16);
            if (p == 0) {
#pragma unroll
                for (int kc = 0; kc < 2; ++kc) {
                    bg[kc] = *(const bf16x8*)(b0 + 32768 + (wj * 2 + kc) * 1024 + lane * 16);
                    bu[kc] = *(const bf16x8*)(b0 + 40960 + (wj * 2 + kc) * 1024 + lane * 16);
                }
            }
            if (st) {   // stage tile t+2: 2,2,1,1 loads across the 4 phases
                if (p == 0)      { GLOAD_LDS16(gbase[0] + kb2, b2 + ldsoff[0]);
                                   GLOAD_LDS16(gbase[1] + kb2, b2 + ldsoff[1]); }
                else if (p == 1) { GLOAD_LDS16(gbase[2] + kb2, b2 + ldsoff[2]);
                                   GLOAD_LDS16(gbase[3] + kb2, b2 + ldsoff[3]); }
                else if (p == 2) { GLOAD_LDS16(gbase[4] + kb2, b2 + ldsoff[4]); }
                else             { GLOAD_LDS16(gbase[5] + kb2, b2 + ldsoff[5]); }
            }
            __builtin_amdgcn_s_setprio(1);
#pragma unroll
            for (int m2 = 0; m2 < 2; ++m2)
#pragma unroll
                for (int kc = 0; kc < 2; ++kc) {
                    accg[p * 2 + m2] = __builtin_amdgcn_mfma_f32_16x16x32_bf16(af[m2][kc], bg[kc], accg[p * 2 + m2], 0, 0, 0);
                    accu[p * 2 + m2] = __builtin_amdgcn_mfma_f32_16x16x32_bf16(af[m2][kc], bu[kc], accu[p * 2 + m2], 0, 0, 0);
                }
            __builtin_amdgcn_s_setprio(0);
            SBAR();
        }
        char* tmp = b0; b0 = b1; b1 = b2; b2 = tmp;
    }

    // epilogue: bias + clamp + GLU, write bf16 intermediate
    int j = j0 + wj * 16 + lm;
    float bgv = bias[e * (2 * F_DIM) + 2 * j];
    float buv = bias[e * (2 * F_DIM) + 2 * j + 1];
#pragma unroll
    for (int mi = 0; mi < 8; ++mi) {
#pragma unroll
        for (int r = 0; r < 4; ++r) {
            int row = row0 + wm * 128 + mi * 16 + lq * 4 + r;
            if (row < row_end) {
                float g = accg[mi][r] + bgv;
                g = fminf(g, 7.0f);
                float u = accu[mi][r] + buv;
                u = fminf(fmaxf(u, -7.0f), 7.0f);
                float glu = g / (1.0f + __expf(-1.702f * g));
                inter[((size_t)row << 11) + j] = f2bf((u + 1.0f) * glu);
            }
        }
    }
}

// GEMM2: inter[TK][2048] x W2t[e][1024][2048] -> out2 f32 [TK][1024]
// Same schedule; 256 rows x 128 n per block, per-wave 128 rows x 32 n, NT=32.
__global__ __launch_bounds__(512) void k_gemm2(
    const ushort_t* __restrict__ Ain, const ushort_t* __restrict__ W2t,
    float* __restrict__ out2, const int* __restrict__ meta) {
    int nt = meta[64];
    int slot = blockIdx.y;
    if (slot >= nt) return;
    int row0    = meta[128 + slot * 3 + 0];
    int row_end = meta[128 + slot * 3 + 1];
    int e       = meta[128 + slot * 3 + 2];
    int n0 = blockIdx.x * 128;
    int tid = threadIdx.x, lane = tid & 63, wid = tid >> 6;
    int wm = wid & 1, wn = wid >> 1;
    int lm = lane & 15, lq = lane >> 4;
    __shared__ char smem[3][48 * 1024];   // per buf: 32 A frags + 16 B frags

    const ushort_t* gbase[6];
    int ldsoff[6];
#pragma unroll
    for (int i = 0; i < 6; ++i) {
        int f = wid * 6 + i;
        if (f < 32) {
            int mb = f >> 1, kc = f & 1;
            int r = row0 + mb * 16 + lm;
            if (r > TK - 1) r = TK - 1;
            gbase[i] = Ain + ((size_t)r << 11) + kc * 32 + lq * 8;
            ldsoff[i] = f * 1024;
        } else {
            int q = f - 32; int nb = q >> 1, kc = q & 1;
            int n = n0 + nb * 16 + lm;
            gbase[i] = W2t + (((size_t)(e * H_DIM + n)) << 11) + kc * 32 + lq * 8;
            ldsoff[i] = 32768 + q * 1024;
        }
    }

    f32x4 acc[8][2];
#pragma unroll
    for (int mi = 0; mi < 8; ++mi)
#pragma unroll
        for (int ni = 0; ni < 2; ++ni) acc[mi][ni] = (f32x4){0.f, 0.f, 0.f, 0.f};

    char* b0 = (char*)smem;
    char* b1 = b0 + 49152;
    char* b2 = b0 + 98304;
#pragma unroll
    for (int i = 0; i < 6; ++i) GLOAD_LDS16(gbase[i], b0 + ldsoff[i]);
#pragma unroll
    for (int i = 0; i < 6; ++i) GLOAD_LDS16(gbase[i] + 64, b1 + ldsoff[i]);

    for (int t = 0; t < 32; ++t) {
        if (t == 31) { WAIT_VM0(); } else { WAIT_VM6(); }
        SBAR();
        bool st = (t < 30);
        int kb2 = (t + 2) * 64;
        bf16x8 bb[2][2];
#pragma unroll
        for (int p = 0; p < 4; ++p) {
            bf16x8 af[2][2];
#pragma unroll
            for (int m2 = 0; m2 < 2; ++m2)
#pragma unroll
                for (int kc = 0; kc < 2; ++kc)
                    af[m2][kc] = *(const bf16x8*)(b0 + ((wm * 8 + p * 2 + m2) * 2 + kc) * 1024 + lane * 16);
            if (p == 0) {
#pragma unroll
                for (int ni = 0; ni < 2; ++ni)
#pragma unroll
                    for (int kc = 0; kc < 2; ++kc)
                        bb[ni][kc] = *(const bf16x8*)(b0 + 32768 + ((wn * 2 + ni) * 2 + kc) * 1024 + lane * 16);
            }
            if (st) {
                if (p == 0)      { GLOAD_LDS16(gbase[0] + kb2, b2 + ldsoff[0]);
                                   GLOAD_LDS16(gbase[1] + kb2, b2 + ldsoff[1]); }
                else if (p == 1) { GLOAD_LDS16(gbase[2] + kb2, b2 + ldsoff[2]);
                                   GLOAD_LDS16(gbase[3] + kb2, b2 + ldsoff[3]); }
                else if (p == 2) { GLOAD_LDS16(gbase[4] + kb2, b2 + ldsoff[4]); }
                else             { GLOAD_LDS16(gbase[5] + kb2, b2 + ldsoff[5]); }
            }
            __builtin_amdgcn_s_setprio(1);
#pragma unroll
            for (int m2 = 0; m2 < 2; ++m2)
#pragma unroll
                for (int ni = 0; ni < 2; ++ni)
#pragma unroll
                    for (int kc = 0; kc < 2; ++kc)
                        acc[p * 2 + m2][ni] = __builtin_amdgcn_mfma_f32_16x16x32_bf16(af[m2][kc], bb[ni][kc], acc[p * 2 + m2][ni], 0, 0, 0);
            __builtin_amdgcn_s_setprio(0);
            SBAR();
        }
        char* tmp = b0; b0 = b1; b1 = b2; b2 = tmp;
    }

#pragma unroll
    for (int mi = 0; mi < 8; ++mi)
#pragma unroll
        for (int ni = 0; ni < 2; ++ni) {
            int n = n0 + (wn * 2 + ni) * 16 + lm;
#pragma unroll
            for (int r = 0; r < 4; ++r) {
                int row = row0 + wm * 128 + mi * 16 + lq * 4 + r;
                if (row < row_end)
                    out2[((size_t)row << 10) + n] = acc[mi][ni][r];
            }
        }
}

// combine: out[t][h] = sum_k w[t][k] * (out2[pos(t,k)][h] + down_bias[e(t,k)][h])
__global__ void k_combine(const float* __restrict__ out2, const float* __restrict__ tw,
                          const int* __restrict__ ids, const float* __restrict__ db,
                          const int* __restrict__ pos2slot, float* __restrict__ out) {
    int t = blockIdx.x;
    int tid = threadIdx.x;
    float w0 = tw[2 * t], w1 = tw[2 * t + 1];
    int p0 = pos2slot[2 * t], p1 = pos2slot[2 * t + 1];
    int e0 = ids[2 * t], e1 = ids[2 * t + 1];
    int h = tid * 4;
    float4 a0 = *(const float4*)(out2 + ((size_t)p0 << 10) + h);
    float4 a1 = *(const float4*)(out2 + ((size_t)p1 << 10) + h);
    float4 b0 = *(const float4*)(db + ((size_t)e0 << 10) + h);
    float4 b1 = *(const float4*)(db + ((size_t)e1 << 10) + h);
    float4 o;
    o.x = w0 * (a0.x + b0.x) + w1 * (a1.x + b1.x);
    o.y = w0 * (a0.y + b0.y) + w1 * (a1.y + b1.y);
    o.z = w0 * (a0.z + b0.z) + w1 * (a1.z + b1.z);
    o.w = w0 * (a0.w + b0.w) + w1 * (a1.w + b1.w);
    *(float4*)(out + (size_t)t * H_DIM + h) = o;
}

// ---------- workspace layout (bytes) ----------
#define WS_META      0              // 8192
#define WS_R2S       8192           // 131072
#define WS_P2S       139264        // 131072 -> 270336
#define WS_A1        270336        // 67108864 -> 67379200   (bf16 A)
#define WS_W1G       67379200      // 67108864 -> 134488064  (reused as out2 f32 after gemm1)
#define WS_W1U       134488064     // 67108864 -> 201596928
#define WS_W2T       201596928     // 67108864 -> 268705792
#define WS_INTER     268705792     // 134217728 -> 402923520

extern "C" void kernel_launch(void* const* d_in, const int* in_sizes, int n_in,
                              void* d_out, int out_size, void* d_ws, size_t ws_size,
                              hipStream_t stream) {
    (void)in_sizes; (void)n_in; (void)out_size; (void)ws_size;
    const float* hs  = (const float*)d_in[0];
    const float* tw  = (const float*)d_in[1];
    const int*   ids = (const int*)d_in[2];
    const float* gup = (const float*)d_in[3];
    const float* gub = (const float*)d_in[4];
    const float* dp  = (const float*)d_in[5];
    const float* dpb = (const float*)d_in[6];
    float* out = (float*)d_out;
    char* ws = (char*)d_ws;

    int* meta          = (int*)(ws + WS_META);
    int* row2slot      = (int*)(ws + WS_R2S);
    int* pos2slot      = (int*)(ws + WS_P2S);
    ushort_t* A1       = (ushort_t*)(ws + WS_A1);
    ushort_t* W1g      = (ushort_t*)(ws + WS_W1G);
    ushort_t* W1u      = (ushort_t*)(ws + WS_W1U);
    ushort_t* W2t      = (ushort_t*)(ws + WS_W2T);
    ushort_t* inter    = (ushort_t*)(ws + WS_INTER);
    float* out2        = (float*)(ws + WS_W1G);   // alias: W1g/W1u dead after gemm1

    hipMemsetAsync(meta, 0, 8192, stream);
    k_hist<<<128, 256, 0, stream>>>(ids, meta);
    k_scan<<<1, 64, 0, stream>>>(meta);
    k_scatter<<<128, 256, 0, stream>>>(ids, meta, row2slot, pos2slot);
    k_gather<<<TK, 256, 0, stream>>>(hs, row2slot, A1);
    k_w1conv<<<16384, 256, 0, stream>>>(gup, W1g, W1u);
    k_w2conv<<<8192, 256, 0, stream>>>(dp, W2t);
    k_gemm1<<<dim3(32, MAX_TILES), 512, 0, stream>>>(A1, W1g, W1u, gub, inter, meta);
    k_gemm2<<<dim3(8, MAX_TILES), 512, 0, stream>>>(inter, W2t, out2, meta);
    k_combine<<<T_TOK, 256, 0, stream>>>(out2, tw, ids, dpb, pos2slot, out);
}